// Round 12
// baseline (147.864 us; speedup 1.0000x reference)
//
#include <hip/hip_runtime.h>

typedef __attribute__((ext_vector_type(8))) short short8;
typedef __attribute__((ext_vector_type(4))) float float4f;

#define PITCH 136   // shorts/row in LDS planes
#define ROWS 32     // rows per fwd block
#define LOG_SLOPE -2.302585092994046f   // log(0.1)
#define LN2 0.6931471805599453f
#define NBLK 140    // 12 LU + 128 fwd
#define LDS_BYTES 69760   // 8 planes * 32*136*2 + 128 cnt
// ws layout (floats): [0] ticket | [2..13] logdet partials | [64..4159] counts

__device__ __forceinline__ float bf2f(unsigned int u) {
    return __builtin_bit_cast(float, u << 16);
}
__device__ __forceinline__ unsigned short f2bf(float f) {
    unsigned int x = __builtin_bit_cast(unsigned int, f);
    x += 0x7fff + ((x >> 16) & 1);   // round-to-nearest-even
    return (unsigned short)(x >> 16);
}
__device__ __forceinline__ float4f vmsub(float4f a, float s, float4f b) {
    a[0] -= s * b[0]; a[1] -= s * b[1]; a[2] -= s * b[2]; a[3] -= s * b[3];
    return a;
}

template<int ISF32>
__device__ __forceinline__ float ldv(const void* p, int i) {
    if (ISF32) return ((const float*)p)[i];
    return bf2f(((const unsigned short*)p)[i]);
}

// Per-wave dtype sniff: fp32 weights read as u16 pairs have uniform-random
// mantissa halves; bf16 weights have exponent fields in a narrow band.
__device__ __forceinline__ int detect_f32(const unsigned short* W1u, int lane) {
    unsigned int u = W1u[lane * 2];
    unsigned int e = (u >> 7) & 0xFF;
    int bad = (e < 64) || (e > 135);
    return __ballot(bad) != 0ull;
}

__device__ __forceinline__ float4f mfma16(short8 a, short8 b, float4f c) {
    return __builtin_amdgcn_mfma_f32_16x16x32_bf16(a, b, c, 0, 0, 0);
}

__device__ __forceinline__ void split8(float4f a, float4f b, short8& hi, short8& lo) {
#pragma unroll
    for (int j = 0; j < 4; ++j) {
        float v = a[j]; unsigned short h = f2bf(v);
        hi[j] = (short)h; lo[j] = (short)f2bf(v - bf2f(h));
        v = b[j]; h = f2bf(v);
        hi[4 + j] = (short)h; lo[4 + j] = (short)f2bf(v - bf2f(h));
    }
}

// Converted weight fragments for one matvec: [kk]{w0h,w1h,w0l,w1l}.
struct W8 { short8 v[16]; };
// Raw prefetch buffers (held in registers across a matvec).
template<int ISF32> struct WRaw;
template<> struct WRaw<1> { float4f v[16]; };   // [kk]{c0a,c0b,c1a,c1b}
template<> struct WRaw<0> { short8 v[8];  };    // [kk]{c0,c1}

template<int ISF32>
__device__ __forceinline__ WRaw<ISF32> loadRaw(const void* W, int c0, int c1, int q);
template<>
__device__ __forceinline__ WRaw<1> loadRaw<1>(const void* W, int c0, int c1, int q) {
    WRaw<1> r;
    const float* p = (const float*)W;
#pragma unroll
    for (int kk = 0; kk < 4; ++kk) {
        const int kc = kk * 32 + q * 8;
        r.v[kk * 4 + 0] = *(const float4f*)(p + c0 * 128 + kc);
        r.v[kk * 4 + 1] = *(const float4f*)(p + c0 * 128 + kc + 4);
        r.v[kk * 4 + 2] = *(const float4f*)(p + c1 * 128 + kc);
        r.v[kk * 4 + 3] = *(const float4f*)(p + c1 * 128 + kc + 4);
    }
    return r;
}
template<>
__device__ __forceinline__ WRaw<0> loadRaw<0>(const void* W, int c0, int c1, int q) {
    WRaw<0> r;
    const unsigned short* p = (const unsigned short*)W;
#pragma unroll
    for (int kk = 0; kk < 4; ++kk) {
        const int kc = kk * 32 + q * 8;
        r.v[kk * 2 + 0] = *(const short8*)(p + c0 * 128 + kc);
        r.v[kk * 2 + 1] = *(const short8*)(p + c1 * 128 + kc);
    }
    return r;
}

template<int ISF32>
__device__ __forceinline__ W8 convertW(const WRaw<ISF32>& raw);
template<>
__device__ __forceinline__ W8 convertW<1>(const WRaw<1>& raw) {
    W8 w;
#pragma unroll
    for (int kk = 0; kk < 4; ++kk) {
        split8(raw.v[kk * 4 + 0], raw.v[kk * 4 + 1], w.v[kk * 4 + 0], w.v[kk * 4 + 2]);
        split8(raw.v[kk * 4 + 2], raw.v[kk * 4 + 3], w.v[kk * 4 + 1], w.v[kk * 4 + 3]);
    }
    return w;
}
template<>
__device__ __forceinline__ W8 convertW<0>(const WRaw<0>& raw) {
    W8 w;
    const short8 z = {0, 0, 0, 0, 0, 0, 0, 0};
#pragma unroll
    for (int kk = 0; kk < 4; ++kk) {
        w.v[kk * 4 + 0] = raw.v[kk * 2 + 0];
        w.v[kk * 4 + 1] = raw.v[kk * 2 + 1];
        w.v[kk * 4 + 2] = z;
        w.v[kk * 4 + 3] = z;
    }
    return w;
}

template<int ISF32>
__device__ __forceinline__ const void* wptr(const void* W, int ofs) {
    return ISF32 ? (const void*)((const float*)W + ofs)
                 : (const void*)((const unsigned short*)W + ofs);
}

// out[ROWS x 128] = act( in[ROWS x 128] @ W^T + bias ); ping-pong LDS planes,
// one barrier per matvec. This matvec's weights arrive converted in `w`; the
// NEXT matvec's RAW weights are prefetched right after the barrier and
// converted in the MFMA shadow (r11: prefetch = -10us; r7: inline split is
// free under load shadows).
// MODE 0: out = leaky(v) | 1: out = res + v | 2: out = leaky(v)+count | 3: count only
template<int MODE, int ISF32>
__device__ __forceinline__ W8 matvec(const W8& w,
        const unsigned short* inh, const unsigned short* inl,
        unsigned short* outh, unsigned short* outl,
        const unsigned short* resh, const unsigned short* resl,
        const void* __restrict__ nw,            // next matvec's raw W
        const void* __restrict__ bias, int bofs,
        int lane, int colb, int* cnt) {
    const int m = lane & 15, q = lane >> 4;
    const int c0 = colb + m, c1 = colb + 16 + m;
    float b0 = ldv<ISF32>(bias, bofs + c0);
    float b1v = ldv<ISF32>(bias, bofs + c1);
    float4f acc[2][2];
#pragma unroll
    for (int rt = 0; rt < 2; ++rt) {
        acc[rt][0] = (float4f){b0, b0, b0, b0};
        acc[rt][1] = (float4f){b1v, b1v, b1v, b1v};
    }
    __syncthreads();   // previous matvec's LDS writes visible
    WRaw<ISF32> raw = loadRaw<ISF32>(nw, c0, c1, q);   // prefetch next weights
#pragma unroll
    for (int kk = 0; kk < 4; ++kk) {
        const int kc = kk * 32 + q * 8;
#pragma unroll
        for (int rt = 0; rt < 2; ++rt) {
            short8 xh = *(const short8*)(inh + (rt * 16 + m) * PITCH + kc);
            short8 xl = *(const short8*)(inl + (rt * 16 + m) * PITCH + kc);
            acc[rt][0] = mfma16(xh, w.v[kk * 4 + 0], acc[rt][0]);
            acc[rt][0] = mfma16(xl, w.v[kk * 4 + 0], acc[rt][0]);
            acc[rt][0] = mfma16(xh, w.v[kk * 4 + 2], acc[rt][0]);
            acc[rt][1] = mfma16(xh, w.v[kk * 4 + 1], acc[rt][1]);
            acc[rt][1] = mfma16(xl, w.v[kk * 4 + 1], acc[rt][1]);
            acc[rt][1] = mfma16(xh, w.v[kk * 4 + 3], acc[rt][1]);
        }
    }
    W8 wn = convertW<ISF32>(raw);   // waits the prefetch; VALU in MFMA shadow
    int c[2][4];
#pragma unroll
    for (int rt = 0; rt < 2; ++rt) {
#pragma unroll
        for (int r = 0; r < 4; ++r) {
            float v0 = acc[rt][0][r], v1 = acc[rt][1][r];
            int row = rt * 16 + q * 4 + r;
            int o0 = row * PITCH + c0, o1 = row * PITCH + c1;
            if (MODE == 1) {
                v0 += bf2f(resh[o0]) + bf2f(resl[o0]);
                v1 += bf2f(resh[o1]) + bf2f(resl[o1]);
            }
            if (MODE >= 2) c[rt][r] = (v0 <= 0.0f) + (v1 <= 0.0f);
            if (MODE == 0 || MODE == 2) {
                v0 = v0 > 0.0f ? v0 : 0.1f * v0;
                v1 = v1 > 0.0f ? v1 : 0.1f * v1;
            }
            if (MODE != 3) {
                unsigned short h0 = f2bf(v0);
                outh[o0] = h0; outl[o0] = f2bf(v0 - bf2f(h0));
                unsigned short h1 = f2bf(v1);
                outh[o1] = h1; outl[o1] = f2bf(v1 - bf2f(h1));
            }
        }
    }
    if (MODE >= 2) {
#pragma unroll
        for (int rt = 0; rt < 2; ++rt) {
#pragma unroll
            for (int r = 0; r < 4; ++r) {
                int cc = c[rt][r];
                cc += __shfl_xor(cc, 1);
                cc += __shfl_xor(cc, 2);
                cc += __shfl_xor(cc, 4);
                cc += __shfl_xor(cc, 8);
                if (m == 0) atomicAdd(&cnt[rt * 16 + q * 4 + r], cc);
            }
        }
    }
    return wn;
}

template<int ISF32>
__device__ __forceinline__ void fwd(int bid, int tid, int lane, char* ldsb,
        const void* x, const void* W1, const void* b1, const void* W2,
        const void* b2, const void* W3, const void* b3, void* out, float* wsw) {
    unsigned short* P = (unsigned short*)ldsb;
    unsigned short* Ah = P;
    unsigned short* Al = P + 1 * ROWS * PITCH;
    unsigned short* Bh = P + 2 * ROWS * PITCH;
    unsigned short* Bl = P + 3 * ROWS * PITCH;
    unsigned short* Th = P + 4 * ROWS * PITCH;
    unsigned short* Tl = P + 5 * ROWS * PITCH;
    unsigned short* Uh = P + 6 * ROWS * PITCH;
    unsigned short* Ul = P + 7 * ROWS * PITCH;
    int* cnt = (int*)(P + 8 * ROWS * PITCH);
    const int r0 = bid * ROWS;
    const int m = lane & 15, q = lane >> 4;
    const int colb = (tid >> 6) * 32;
    const int c0 = colb + m, c1 = colb + 16 + m;
    // prefetch + convert layer-0 w1 while staging x into LDS
    WRaw<ISF32> raw0 = loadRaw<ISF32>(W1, c0, c1, q);
    for (int e = tid; e < ROWS * 128; e += 256) {
        int r = e >> 7, c = e & 127;
        float v = ldv<ISF32>(x, (r0 + r) * 128 + c);
        unsigned short h = f2bf(v);
        Ah[r * PITCH + c] = h;
        Al[r * PITCH + c] = f2bf(v - bf2f(h));
    }
    if (tid < ROWS) cnt[tid] = 0;
    W8 wcur = convertW<ISF32>(raw0);
    unsigned short *curh = Ah, *curl = Al, *othh = Bh, *othl = Bl;
#pragma unroll 1
    for (int layer = 0; layer < 4; ++layer) {
        const int wofs = layer * 16384, bofs = layer * 128;
        const void* w1p = wptr<ISF32>(W1, wofs);
        const void* w2p = wptr<ISF32>(W2, wofs);
        const void* w3p = wptr<ISF32>(W3, wofs);
        const void* n1p = wptr<ISF32>(W1, ((layer + 1) & 3) * 16384);
        wcur = matvec<0, ISF32>(wcur, curh, curl, Th, Tl, 0, 0, w2p, b1, bofs, lane, colb, cnt);
        wcur = matvec<0, ISF32>(wcur, Th, Tl, Uh, Ul, 0, 0, w3p, b2, bofs, lane, colb, cnt);
        wcur = matvec<1, ISF32>(wcur, Uh, Ul, othh, othl, curh, curl, w1p, b3, bofs, lane, colb, cnt);
        wcur = matvec<2, ISF32>(wcur, othh, othl, Th, Tl, 0, 0, w2p, b1, bofs, lane, colb, cnt);
        wcur = matvec<3, ISF32>(wcur, Th, Tl, Th, Tl, 0, 0, n1p, b2, bofs, lane, colb, cnt);
        unsigned short* t;
        t = curh; curh = othh; othh = t;
        t = curl; curl = othl; othl = t;
    }
    __syncthreads();
    for (int e = tid; e < ROWS * 128; e += 256) {
        int r = e >> 7, c = e & 127;
        float v = bf2f(curh[r * PITCH + c]) + bf2f(curl[r * PITCH + c]);
        if (ISF32) ((float*)out)[(r0 + r) * 128 + c] = v;
        else ((unsigned short*)out)[(r0 + r) * 128 + c] = f2bf(v);
    }
    if (tid < ROWS) wsw[64 + r0 + tid] = (float)cnt[tid];
}

// ---- register-resident unpivoted LU, RANK-4 per barrier (32 intervals).
// Per interval: stage 4 pivot rows + 4 pivot cols (double-buffered LDS);
// every thread redundantly factors the 4x4 diagonal block in registers and
// applies one rank-4 update to its V[16]. All register indices compile-time
// (r6 lesson: dynamic reg index -> scratch demotion).
template<int ISF32>
__device__ __forceinline__ float lu_logdet(int id, int tid, float* lds,
        const void* W1, const void* W2, const void* W3) {
    const int wsel = id % 3;
    const void* Wm = (wsel == 0 ? W1 : (wsel == 1 ? W2 : W3));
    const int ofs = (id / 3) * 16384;
    const int tx = tid & 31, ty = tid >> 5;
    float* rowbuf = lds;          // [2][4][128]: rows K..K+3
    float* colbuf = lds + 1024;   // [2][4][128]: cols K..K+3 packed [j][ty*16+m]
    float4f V[16];                // A[ty+8m][4tx..4tx+3]
#pragma unroll
    for (int m = 0; m < 16; ++m) {
        int base = ofs + (ty + 8 * m) * 128 + 4 * tx;
        if (ISF32) {
            V[m] = *(const float4f*)((const float*)Wm + base);
        } else {
            ushort4 u = *(const ushort4*)((const unsigned short*)Wm + base);
            V[m] = (float4f){bf2f(u.x), bf2f(u.y), bf2f(u.z), bf2f(u.w)};
        }
    }
    // stage interval 0: rows 0..3 (ty 0..3, all m=0), cols 0..3 (owner tx==0)
    if (ty < 4) *(float4f*)&rowbuf[ty * 128 + 4 * tx] = V[0];
    if (tx == 0) {
#pragma unroll
        for (int j = 0; j < 4; ++j) {
#pragma unroll
            for (int mg = 0; mg < 4; ++mg) {
                float4f t = {V[mg * 4 + 0][j], V[mg * 4 + 1][j],
                             V[mg * 4 + 2][j], V[mg * 4 + 3][j]};
                *(float4f*)&colbuf[j * 128 + ty * 16 + mg * 4] = t;
            }
        }
    }
    __syncthreads();
    float logacc = 0.0f;
#pragma unroll 1
    for (int kap = 0; kap < 32; ++kap) {
        const int K = kap * 4;
        const int buf = (kap & 1) * 512;
        float4f D[4], R[4], C[4][4];
#pragma unroll
        for (int j = 0; j < 4; ++j) {
            D[j] = *(const float4f*)&rowbuf[buf + j * 128 + K];       // broadcast
            R[j] = *(const float4f*)&rowbuf[buf + j * 128 + 4 * tx];
#pragma unroll
            for (int mg = 0; mg < 4; ++mg)
                C[j][mg] = *(const float4f*)&colbuf[buf + j * 128 + ty * 16 + mg * 4];
        }
        // 4x4 panel factorization, redundant per thread
        float p0 = D[0][0], i0 = 1.0f / p0;
        float l10 = D[1][0] * i0, l20 = D[2][0] * i0, l30 = D[3][0] * i0;
        D[1] = vmsub(D[1], l10, D[0]); R[1] = vmsub(R[1], l10, R[0]);
        D[2] = vmsub(D[2], l20, D[0]); R[2] = vmsub(R[2], l20, R[0]);
        D[3] = vmsub(D[3], l30, D[0]); R[3] = vmsub(R[3], l30, R[0]);
        float p1 = D[1][1], i1 = 1.0f / p1;
        float l21 = D[2][1] * i1, l31 = D[3][1] * i1;
        D[2] = vmsub(D[2], l21, D[1]); R[2] = vmsub(R[2], l21, R[1]);
        D[3] = vmsub(D[3], l31, D[1]); R[3] = vmsub(R[3], l31, R[1]);
        float p2 = D[2][2], i2 = 1.0f / p2;
        float l32 = D[3][2] * i2;
        D[3] = vmsub(D[3], l32, D[2]); R[3] = vmsub(R[3], l32, R[2]);
        float p3 = D[3][3], i3 = 1.0f / p3;
        logacc += __log2f(fabsf(p0)) + __log2f(fabsf(p1))
                + __log2f(fabsf(p2)) + __log2f(fabsf(p3));
        float iv[4] = {i0, i1, i2, i3};
        // cols -> multipliers in place (masked per row), propagate to later cols
#pragma unroll
        for (int i = 0; i < 4; ++i) {
#pragma unroll
            for (int mg = 0; mg < 4; ++mg) {
#pragma unroll
                for (int e = 0; e < 4; ++e) {
                    int r = ty + 32 * mg + 8 * e;
                    C[i][mg][e] = (r > K + i) ? C[i][mg][e] * iv[i] : 0.0f;
                }
            }
#pragma unroll
            for (int j = i + 1; j < 4; ++j) {
                float uij = D[i][j];
#pragma unroll
                for (int mg = 0; mg < 4; ++mg)
                    C[j][mg] = vmsub(C[j][mg], uij, C[i][mg]);
            }
        }
        // rank-4 trailing update
#pragma unroll
        for (int mg = 0; mg < 4; ++mg) {
#pragma unroll
            for (int e = 0; e < 4; ++e) {
                float4f v = V[mg * 4 + e];
                v = vmsub(v, C[0][mg][e], R[0]);
                v = vmsub(v, C[1][mg][e], R[1]);
                v = vmsub(v, C[2][mg][e], R[2]);
                v = vmsub(v, C[3][mg][e], R[3]);
                V[mg * 4 + e] = v;
            }
        }
        // stage next interval (rows/cols K+4..K+7)
        if (kap < 31) {
            const int nbuf = ((kap + 1) & 1) * 512;
            const int tb = (kap & 1) ? 0 : 4;     // rows K+4..K+7 -> ty in [tb,tb+4)
            const int mn = (kap + 1) >> 1;        // their m index (uniform)
            if (ty >= tb && ty < tb + 4) {
                float4f val;
                switch (mn) {                     // uniform switch, static reg index
                case 0:  val = V[0];  break; case 1:  val = V[1];  break;
                case 2:  val = V[2];  break; case 3:  val = V[3];  break;
                case 4:  val = V[4];  break; case 5:  val = V[5];  break;
                case 6:  val = V[6];  break; case 7:  val = V[7];  break;
                case 8:  val = V[8];  break; case 9:  val = V[9];  break;
                case 10: val = V[10]; break; case 11: val = V[11]; break;
                case 12: val = V[12]; break; case 13: val = V[13]; break;
                case 14: val = V[14]; break; default: val = V[15]; break;
                }
                *(float4f*)&rowbuf[nbuf + (ty - tb) * 128 + 4 * tx] = val;
            }
            if (tx == kap + 1) {   // owner of cols K+4..K+7 (4-aligned)
#pragma unroll
                for (int j = 0; j < 4; ++j) {
#pragma unroll
                    for (int mg = 0; mg < 4; ++mg) {
                        float4f t = {V[mg * 4 + 0][j], V[mg * 4 + 1][j],
                                     V[mg * 4 + 2][j], V[mg * 4 + 3][j]};
                        *(float4f*)&colbuf[nbuf + j * 128 + ty * 16 + mg * 4] = t;
                    }
                }
            }
        }
        __syncthreads();   // one barrier per 4 pivots
    }
    return logacc * LN2;
}

__global__ __launch_bounds__(256, 1) void k_main(
        const void* __restrict__ x,
        const void* __restrict__ W1, const void* __restrict__ b1,
        const void* __restrict__ W2, const void* __restrict__ b2,
        const void* __restrict__ W3, const void* __restrict__ b3,
        void* __restrict__ out, float* __restrict__ ws) {
    extern __shared__ __align__(16) char ldsb[];
    __shared__ int s_last;
    const int tid = threadIdx.x;
    const int lane = tid & 63;
    const int isf32 = detect_f32((const unsigned short*)W1, lane);

    if (blockIdx.x < 12) {
        float ld = isf32 ? lu_logdet<1>(blockIdx.x, tid, (float*)ldsb, W1, W2, W3)
                         : lu_logdet<0>(blockIdx.x, tid, (float*)ldsb, W1, W2, W3);
        if (tid == 0) ws[2 + blockIdx.x] = ld;
    } else {
        const int bid = blockIdx.x - 12;
        if (isf32) fwd<1>(bid, tid, lane, ldsb, x, W1, b1, W2, b2, W3, b3, out, ws);
        else       fwd<0>(bid, tid, lane, ldsb, x, W1, b1, W2, b2, W3, b3, out, ws);
    }

    // ---- last-block finalize ----
    __threadfence();
    if (tid == 0) s_last = (atomicAdd((int*)ws, 1) == NBLK - 1);
    __syncthreads();
    if (!s_last) return;
    __threadfence();   // acquire: other blocks' ws writes now visible
    float s = 0.0f;
#pragma unroll
    for (int i = 0; i < 12; ++i) s += ws[2 + i];
    for (int b = tid; b < 4096; b += 256) {
        float v = s + LOG_SLOPE * ws[64 + b];
        if (isf32) ((float*)out)[524288 + b] = v;
        else ((unsigned short*)out)[524288 + b] = f2bf(v);
    }
}

extern "C" void kernel_launch(void* const* d_in, const int* in_sizes, int n_in,
                              void* d_out, int out_size, void* d_ws, size_t ws_size,
                              hipStream_t stream) {
    const void* x  = d_in[0];
    const void* W1 = d_in[1];
    const void* b1 = d_in[2];
    const void* W2 = d_in[3];
    const void* b2 = d_in[4];
    const void* W3 = d_in[5];
    const void* b3 = d_in[6];
    float* ws = (float*)d_ws;

    hipMemsetAsync(d_ws, 0, 8, stream);   // zero the finalize ticket
    hipLaunchKernelGGL(k_main, dim3(NBLK), dim3(256), LDS_BYTES, stream,
                       x, W1, b1, W2, b2, W3, b3, d_out, ws);
}

// Round 13
// 146.233 us; speedup vs baseline: 1.0112x; 1.0112x over previous
//
#include <hip/hip_runtime.h>

typedef __attribute__((ext_vector_type(8))) short short8;
typedef __attribute__((ext_vector_type(4))) float float4f;

#define PITCH 136   // shorts/row in LDS planes
#define ROWS 32     // rows per fwd block
#define LOG_SLOPE -2.302585092994046f   // log(0.1)
#define LN2 0.6931471805599453f
#define NBLK 140    // 12 LU + 128 fwd
#define LDS_BYTES 69760   // 8 planes * 32*136*2 + 128 cnt
// ws layout (floats): [0] ticket | [2..13] logdet partials | [64..4159] counts
// [4160..5695] fp32 biases | [8192..] W hi/lo ushort planes
#define WS_BIAS 4160
#define WS_WPLANES 8192
#define NWELEM 196608   // 12 * 16384

__device__ __forceinline__ float bf2f(unsigned int u) {
    return __builtin_bit_cast(float, u << 16);
}
__device__ __forceinline__ unsigned short f2bf(float f) {
    unsigned int x = __builtin_bit_cast(unsigned int, f);
    x += 0x7fff + ((x >> 16) & 1);   // round-to-nearest-even
    return (unsigned short)(x >> 16);
}
__device__ __forceinline__ float4f vmsub(float4f a, float s, float4f b) {
    a[0] -= s * b[0]; a[1] -= s * b[1]; a[2] -= s * b[2]; a[3] -= s * b[3];
    return a;
}

template<int ISF32>
__device__ __forceinline__ float ldv(const void* p, int i) {
    if (ISF32) return ((const float*)p)[i];
    return bf2f(((const unsigned short*)p)[i]);
}

// Per-wave dtype sniff: fp32 weights read as u16 pairs have uniform-random
// mantissa halves; bf16 weights have exponent fields in a narrow band.
__device__ __forceinline__ int detect_f32(const unsigned short* W1u, int lane) {
    unsigned int u = W1u[lane * 2];
    unsigned int e = (u >> 7) & 0xFF;
    int bad = (e < 64) || (e > 135);
    return __ballot(bad) != 0ull;
}

__device__ __forceinline__ float4f mfma16(short8 a, short8 b, float4f c) {
    return __builtin_amdgcn_mfma_f32_16x16x32_bf16(a, b, c, 0, 0, 0);
}

__device__ __forceinline__ void split8(float4f a, float4f b, short8& hi, short8& lo) {
#pragma unroll
    for (int j = 0; j < 4; ++j) {
        float v = a[j]; unsigned short h = f2bf(v);
        hi[j] = (short)h; lo[j] = (short)f2bf(v - bf2f(h));
        v = b[j]; h = f2bf(v);
        hi[4 + j] = (short)h; lo[4 + j] = (short)f2bf(v - bf2f(h));
    }
}

// ---- prep: W -> bf16 hi/lo planes, biases -> fp32, zero ticket ----
// (r12 lesson: inline per-matvec conversion costs ~450 cyc/matvec on the fwd
// critical path — the separate prep node is effectively free.)
__global__ void k_prep(const void* __restrict__ W1, const void* __restrict__ W2,
                       const void* __restrict__ W3, const void* __restrict__ b1,
                       const void* __restrict__ b2, const void* __restrict__ b3,
                       float* __restrict__ ws) {
    const int tid = threadIdx.x, bid = blockIdx.x;
    const int isf32 = detect_f32((const unsigned short*)W1, tid & 63);
    unsigned short* whi = (unsigned short*)(ws + WS_WPLANES);
    unsigned short* wlo = whi + NWELEM;
    if (bid < 96) {
        int s = (bid * 256 + tid) * 8;        // 96*256*8 = 196608
        int mat = s >> 14, off = s & 16383;   // mat = wsel*4 + layer
        int wsel = mat >> 2;
        const void* Wm = wsel == 0 ? W1 : (wsel == 1 ? W2 : W3);
        int src = (mat & 3) * 16384 + off;
        short8 hi, lo;
        if (isf32) {
            const float* p = (const float*)Wm + src;
            split8(*(const float4f*)p, *(const float4f*)(p + 4), hi, lo);
        } else {
            hi = *(const short8*)((const unsigned short*)Wm + src);
            lo = (short8){0, 0, 0, 0, 0, 0, 0, 0};
        }
        *(short8*)(whi + s) = hi;
        *(short8*)(wlo + s) = lo;
    } else {
        for (int e = tid; e < 1536; e += 256) {
            int bsel = e >> 9, idx = e & 511;
            const void* bp = bsel == 0 ? b1 : (bsel == 1 ? b2 : b3);
            ws[WS_BIAS + e] = isf32 ? ((const float*)bp)[idx]
                                    : bf2f(((const unsigned short*)bp)[idx]);
        }
        if (tid == 0) ((int*)ws)[0] = 0;   // finalize ticket
    }
}

// Weight fragment set for one matvec: [kk]{w0h,w1h,w0l,w1l}. All static indices.
struct W8 { short8 v[16]; };

__device__ __forceinline__ W8 loadW(const unsigned short* __restrict__ wh,
                                    const unsigned short* __restrict__ wl,
                                    int c0, int c1, int q) {
    W8 r;
#pragma unroll
    for (int kk = 0; kk < 4; ++kk) {
        const int kc = kk * 32 + q * 8;
        r.v[kk * 4 + 0] = *(const short8*)(wh + c0 * 128 + kc);
        r.v[kk * 4 + 1] = *(const short8*)(wh + c1 * 128 + kc);
        r.v[kk * 4 + 2] = *(const short8*)(wl + c0 * 128 + kc);
        r.v[kk * 4 + 3] = *(const short8*)(wl + c1 * 128 + kc);
    }
    return r;
}

// out[ROWS x 128] = act( in[ROWS x 128] @ W^T + bias ); ping-pong planes,
// one barrier per matvec. Weights for THIS matvec arrive preloaded in `w`;
// the NEXT matvec's weights are prefetched right after the barrier (r11: -10us).
// MODE 0: out = leaky(v) | 1: out = res + v | 2: out = leaky(v)+count | 3: count only
template<int MODE>
__device__ __forceinline__ W8 matvec(const W8& w,
        const unsigned short* inh, const unsigned short* inl,
        unsigned short* outh, unsigned short* outl,
        const unsigned short* resh, const unsigned short* resl,
        const unsigned short* __restrict__ nwh, const unsigned short* __restrict__ nwl,
        const float* __restrict__ bias,
        int lane, int colb, int* cnt) {
    const int m = lane & 15, q = lane >> 4;
    const int c0 = colb + m, c1 = colb + 16 + m;
    float b0 = bias[c0], b1v = bias[c1];
    float4f acc[2][2];
#pragma unroll
    for (int rt = 0; rt < 2; ++rt) {
        acc[rt][0] = (float4f){b0, b0, b0, b0};
        acc[rt][1] = (float4f){b1v, b1v, b1v, b1v};
    }
    __syncthreads();   // previous matvec's LDS writes visible
    W8 wn = loadW(nwh, nwl, c0, c1, q);   // prefetch next matvec's weights
#pragma unroll
    for (int kk = 0; kk < 4; ++kk) {
        const int kc = kk * 32 + q * 8;
#pragma unroll
        for (int rt = 0; rt < 2; ++rt) {
            short8 xh = *(const short8*)(inh + (rt * 16 + m) * PITCH + kc);
            short8 xl = *(const short8*)(inl + (rt * 16 + m) * PITCH + kc);
            acc[rt][0] = mfma16(xh, w.v[kk * 4 + 0], acc[rt][0]);
            acc[rt][0] = mfma16(xl, w.v[kk * 4 + 0], acc[rt][0]);
            acc[rt][0] = mfma16(xh, w.v[kk * 4 + 2], acc[rt][0]);
            acc[rt][1] = mfma16(xh, w.v[kk * 4 + 1], acc[rt][1]);
            acc[rt][1] = mfma16(xl, w.v[kk * 4 + 1], acc[rt][1]);
            acc[rt][1] = mfma16(xh, w.v[kk * 4 + 3], acc[rt][1]);
        }
    }
    int c[2][4];
#pragma unroll
    for (int rt = 0; rt < 2; ++rt) {
#pragma unroll
        for (int r = 0; r < 4; ++r) {
            float v0 = acc[rt][0][r], v1 = acc[rt][1][r];
            int row = rt * 16 + q * 4 + r;
            int o0 = row * PITCH + c0, o1 = row * PITCH + c1;
            if (MODE == 1) {
                v0 += bf2f(resh[o0]) + bf2f(resl[o0]);
                v1 += bf2f(resh[o1]) + bf2f(resl[o1]);
            }
            if (MODE >= 2) c[rt][r] = (v0 <= 0.0f) + (v1 <= 0.0f);
            if (MODE == 0 || MODE == 2) {
                v0 = v0 > 0.0f ? v0 : 0.1f * v0;
                v1 = v1 > 0.0f ? v1 : 0.1f * v1;
            }
            if (MODE != 3) {
                unsigned short h0 = f2bf(v0);
                outh[o0] = h0; outl[o0] = f2bf(v0 - bf2f(h0));
                unsigned short h1 = f2bf(v1);
                outh[o1] = h1; outl[o1] = f2bf(v1 - bf2f(h1));
            }
        }
    }
    if (MODE >= 2) {
#pragma unroll
        for (int rt = 0; rt < 2; ++rt) {
#pragma unroll
            for (int r = 0; r < 4; ++r) {
                int cc = c[rt][r];
                cc += __shfl_xor(cc, 1);
                cc += __shfl_xor(cc, 2);
                cc += __shfl_xor(cc, 4);
                cc += __shfl_xor(cc, 8);
                if (m == 0) atomicAdd(&cnt[rt * 16 + q * 4 + r], cc);
            }
        }
    }
    return wn;
}

template<int ISF32>
__device__ __forceinline__ void fwd(int bid, int tid, int lane, char* ldsb,
                                    const void* x, const float* ws, void* out,
                                    float* wsw) {
    unsigned short* P = (unsigned short*)ldsb;
    unsigned short* Ah = P;
    unsigned short* Al = P + 1 * ROWS * PITCH;
    unsigned short* Bh = P + 2 * ROWS * PITCH;
    unsigned short* Bl = P + 3 * ROWS * PITCH;
    unsigned short* Th = P + 4 * ROWS * PITCH;
    unsigned short* Tl = P + 5 * ROWS * PITCH;
    unsigned short* Uh = P + 6 * ROWS * PITCH;
    unsigned short* Ul = P + 7 * ROWS * PITCH;
    int* cnt = (int*)(P + 8 * ROWS * PITCH);
    const unsigned short* whi = (const unsigned short*)(ws + WS_WPLANES);
    const unsigned short* wlo = whi + NWELEM;
    const float* bias = ws + WS_BIAS;
    const int r0 = bid * ROWS;
    const int m = lane & 15, q = lane >> 4;
    const int colb = (tid >> 6) * 32;
    const int c0 = colb + m, c1 = colb + 16 + m;
    // prefetch layer-0 w1 while staging x into LDS
    W8 wcur = loadW(whi, wlo, c0, c1, q);
    for (int e = tid; e < ROWS * 128; e += 256) {
        int r = e >> 7, c = e & 127;
        float v = ldv<ISF32>(x, (r0 + r) * 128 + c);
        unsigned short h = f2bf(v);
        Ah[r * PITCH + c] = h;
        Al[r * PITCH + c] = f2bf(v - bf2f(h));
    }
    if (tid < ROWS) cnt[tid] = 0;
    unsigned short *curh = Ah, *curl = Al, *othh = Bh, *othl = Bl;
#pragma unroll 1
    for (int layer = 0; layer < 4; ++layer) {
        const unsigned short* w1h = whi + (0 + layer) * 16384;
        const unsigned short* w1l = wlo + (0 + layer) * 16384;
        const unsigned short* w2h = whi + (4 + layer) * 16384;
        const unsigned short* w2l = wlo + (4 + layer) * 16384;
        const unsigned short* w3h = whi + (8 + layer) * 16384;
        const unsigned short* w3l = wlo + (8 + layer) * 16384;
        const unsigned short* n1h = whi + ((layer + 1) & 3) * 16384;  // next-layer w1
        const unsigned short* n1l = wlo + ((layer + 1) & 3) * 16384;
        const float* b1p = bias + layer * 128;
        const float* b2p = bias + 512 + layer * 128;
        const float* b3p = bias + 1024 + layer * 128;
        wcur = matvec<0>(wcur, curh, curl, Th, Tl, 0, 0, w2h, w2l, b1p, lane, colb, cnt);
        wcur = matvec<0>(wcur, Th, Tl, Uh, Ul, 0, 0, w3h, w3l, b2p, lane, colb, cnt);
        wcur = matvec<1>(wcur, Uh, Ul, othh, othl, curh, curl, w1h, w1l, b3p, lane, colb, cnt);
        wcur = matvec<2>(wcur, othh, othl, Th, Tl, 0, 0, w2h, w2l, b1p, lane, colb, cnt);
        wcur = matvec<3>(wcur, Th, Tl, Th, Tl, 0, 0, n1h, n1l, b2p, lane, colb, cnt);
        unsigned short* t;
        t = curh; curh = othh; othh = t;
        t = curl; curl = othl; othl = t;
    }
    __syncthreads();
    for (int e = tid; e < ROWS * 128; e += 256) {
        int r = e >> 7, c = e & 127;
        float v = bf2f(curh[r * PITCH + c]) + bf2f(curl[r * PITCH + c]);
        if (ISF32) ((float*)out)[(r0 + r) * 128 + c] = v;
        else ((unsigned short*)out)[(r0 + r) * 128 + c] = f2bf(v);
    }
    if (tid < ROWS) wsw[64 + r0 + tid] = (float)cnt[tid];
}

// ---- register-resident unpivoted LU, RANK-8 per barrier (16 intervals).
// Stage 8 pivot rows + 8 packed pivot cols (double-buffered); every thread
// redundantly factors the 8x8 diagonal block in registers and applies one
// rank-8 update to its V[16]. 16 barriers total (r10: rank-4/32 barriers was
// 2.2us/interval, latency-dominated — halve the interval count again).
// All register indices compile-time (r6 lesson: dynamic index -> scratch).
template<int ISF32>
__device__ __forceinline__ float lu_logdet(int id, int tid, float* lds,
        const void* W1, const void* W2, const void* W3) {
    const int wsel = id % 3;
    const void* Wm = (wsel == 0 ? W1 : (wsel == 1 ? W2 : W3));
    const int ofs = (id / 3) * 16384;
    const int tx = tid & 31, ty = tid >> 5;
    float* rowbuf = lds;          // [2][8][128]: rows K..K+7
    float* colbuf = lds + 2048;   // [2][8][128]: cols K..K+7 packed [j][ty*16+m]
    float4f V[16];                // A[ty+8m][4tx..4tx+3]
#pragma unroll
    for (int m = 0; m < 16; ++m) {
        int base = ofs + (ty + 8 * m) * 128 + 4 * tx;
        if (ISF32) {
            V[m] = *(const float4f*)((const float*)Wm + base);
        } else {
            ushort4 u = *(const ushort4*)((const unsigned short*)Wm + base);
            V[m] = (float4f){bf2f(u.x), bf2f(u.y), bf2f(u.z), bf2f(u.w)};
        }
    }
    // stage interval 0: rows 0..7 (= row ty, V[0], all threads), cols 0..7
    *(float4f*)&rowbuf[ty * 128 + 4 * tx] = V[0];
    if (tx < 2) {
#pragma unroll
        for (int j0 = 0; j0 < 4; ++j0) {
#pragma unroll
            for (int mg = 0; mg < 4; ++mg) {
                float4f t = {V[mg * 4 + 0][j0], V[mg * 4 + 1][j0],
                             V[mg * 4 + 2][j0], V[mg * 4 + 3][j0]};
                *(float4f*)&colbuf[(tx * 4 + j0) * 128 + ty * 16 + mg * 4] = t;
            }
        }
    }
    __syncthreads();
    float logacc = 0.0f;
#pragma unroll 1
    for (int kap = 0; kap < 16; ++kap) {
        const int K = kap * 8;
        const int buf = (kap & 1) * 1024;
        float4f D[8][2], R[8], C[8][4];
#pragma unroll
        for (int j = 0; j < 8; ++j) {
            D[j][0] = *(const float4f*)&rowbuf[buf + j * 128 + K];      // broadcast
            D[j][1] = *(const float4f*)&rowbuf[buf + j * 128 + K + 4];  // broadcast
            R[j] = *(const float4f*)&rowbuf[buf + j * 128 + 4 * tx];
#pragma unroll
            for (int mg = 0; mg < 4; ++mg)
                C[j][mg] = *(const float4f*)&colbuf[buf + j * 128 + ty * 16 + mg * 4];
        }
        // 8x8 panel factorization, redundant per thread
        float iv[8];
#pragma unroll
        for (int i = 0; i < 8; ++i) {
            float pi = D[i][i >> 2][i & 3];
            float ivi = 1.0f / pi;
            iv[i] = ivi;
            logacc += __log2f(fabsf(pi));
#pragma unroll
            for (int j = i + 1; j < 8; ++j) {
                float l = D[j][i >> 2][i & 3] * ivi;
                D[j][0] = vmsub(D[j][0], l, D[i][0]);
                D[j][1] = vmsub(D[j][1], l, D[i][1]);
                R[j] = vmsub(R[j], l, R[i]);
            }
        }
        // cols -> multipliers (masked per row), propagate to later cols
#pragma unroll
        for (int i = 0; i < 8; ++i) {
#pragma unroll
            for (int mg = 0; mg < 4; ++mg) {
#pragma unroll
                for (int e = 0; e < 4; ++e) {
                    int r = ty + 32 * mg + 8 * e;
                    C[i][mg][e] = (r > K + i) ? C[i][mg][e] * iv[i] : 0.0f;
                }
            }
#pragma unroll
            for (int j = i + 1; j < 8; ++j) {
                float uij = D[i][j >> 2][j & 3];
#pragma unroll
                for (int mg = 0; mg < 4; ++mg)
                    C[j][mg] = vmsub(C[j][mg], uij, C[i][mg]);
            }
        }
        // rank-8 trailing update
#pragma unroll
        for (int mg = 0; mg < 4; ++mg) {
#pragma unroll
            for (int e = 0; e < 4; ++e) {
                float4f v = V[mg * 4 + e];
#pragma unroll
                for (int i = 0; i < 8; ++i)
                    v = vmsub(v, C[i][mg][e], R[i]);
                V[mg * 4 + e] = v;
            }
        }
        // stage next interval: rows K+8..K+15 (= ty + 8*(kap+1), uniform V idx)
        if (kap < 15) {
            const int nbuf = ((kap + 1) & 1) * 1024;
            float4f val;
            switch (kap + 1) {                    // uniform switch, static reg index
            case 1:  val = V[1];  break; case 2:  val = V[2];  break;
            case 3:  val = V[3];  break; case 4:  val = V[4];  break;
            case 5:  val = V[5];  break; case 6:  val = V[6];  break;
            case 7:  val = V[7];  break; case 8:  val = V[8];  break;
            case 9:  val = V[9];  break; case 10: val = V[10]; break;
            case 11: val = V[11]; break; case 12: val = V[12]; break;
            case 13: val = V[13]; break; case 14: val = V[14]; break;
            default: val = V[15]; break;
            }
            *(float4f*)&rowbuf[nbuf + ty * 128 + 4 * tx] = val;
            const int txb = 2 * (kap + 1);        // owners of cols K+8..K+15
            if (tx == txb || tx == txb + 1) {
                const int jb = (tx - txb) * 4;    // 0 or 4
#pragma unroll
                for (int j0 = 0; j0 < 4; ++j0) {
#pragma unroll
                    for (int mg = 0; mg < 4; ++mg) {
                        float4f t = {V[mg * 4 + 0][j0], V[mg * 4 + 1][j0],
                                     V[mg * 4 + 2][j0], V[mg * 4 + 3][j0]};
                        *(float4f*)&colbuf[nbuf + (jb + j0) * 128 + ty * 16 + mg * 4] = t;
                    }
                }
            }
        }
        __syncthreads();   // one barrier per 8 pivots
    }
    return logacc * LN2;
}

__global__ __launch_bounds__(256, 1) void k_main(
        const void* __restrict__ x,
        const void* __restrict__ W1, const void* __restrict__ b1,
        const void* __restrict__ W2, const void* __restrict__ b2,
        const void* __restrict__ W3, const void* __restrict__ b3,
        void* __restrict__ out, float* __restrict__ ws) {
    extern __shared__ __align__(16) char ldsb[];
    __shared__ int s_last;
    const int tid = threadIdx.x;
    const int lane = tid & 63;
    const int isf32 = detect_f32((const unsigned short*)W1, lane);

    if (blockIdx.x < 12) {
        float ld = isf32 ? lu_logdet<1>(blockIdx.x, tid, (float*)ldsb, W1, W2, W3)
                         : lu_logdet<0>(blockIdx.x, tid, (float*)ldsb, W1, W2, W3);
        if (tid == 0) ws[2 + blockIdx.x] = ld;
    } else {
        const int bid = blockIdx.x - 12;
        if (isf32) fwd<1>(bid, tid, lane, ldsb, x, ws, out, ws);
        else       fwd<0>(bid, tid, lane, ldsb, x, ws, out, ws);
    }

    // ---- last-block finalize ----
    __threadfence();
    if (tid == 0) s_last = (atomicAdd((int*)ws, 1) == NBLK - 1);
    __syncthreads();
    if (!s_last) return;
    __threadfence();   // acquire: other blocks' ws writes now visible
    float s = 0.0f;
#pragma unroll
    for (int i = 0; i < 12; ++i) s += ws[2 + i];
    for (int b = tid; b < 4096; b += 256) {
        float v = s + LOG_SLOPE * ws[64 + b];
        if (isf32) ((float*)out)[524288 + b] = v;
        else ((unsigned short*)out)[524288 + b] = f2bf(v);
    }
}

extern "C" void kernel_launch(void* const* d_in, const int* in_sizes, int n_in,
                              void* d_out, int out_size, void* d_ws, size_t ws_size,
                              hipStream_t stream) {
    const void* x  = d_in[0];
    const void* W1 = d_in[1];
    const void* b1 = d_in[2];
    const void* W2 = d_in[3];
    const void* b2 = d_in[4];
    const void* W3 = d_in[5];
    const void* b3 = d_in[6];
    float* ws = (float*)d_ws;

    hipLaunchKernelGGL(k_prep, dim3(97), dim3(256), 0, stream,
                       W1, W2, W3, b1, b2, b3, ws);
    hipLaunchKernelGGL(k_main, dim3(NBLK), dim3(256), LDS_BYTES, stream,
                       x, W1, b1, W2, b2, W3, b3, d_out, ws);
}

// Round 14
// 140.783 us; speedup vs baseline: 1.0503x; 1.0387x over previous
//
#include <hip/hip_runtime.h>

typedef __attribute__((ext_vector_type(8))) short short8;
typedef __attribute__((ext_vector_type(4))) float float4f;

#define PITCH 136   // shorts/row in LDS planes
#define ROWS 32     // rows per fwd block
#define THREADS 512 // 8 waves: halves per-thread work in both LU and fwd
#define LOG_SLOPE -2.302585092994046f   // log(0.1)
#define LN2 0.6931471805599453f
#define NBLK 140    // 12 LU + 128 fwd
#define LDS_BYTES 69760
// ws layout (floats): [0] ticket | [2..13] logdet partials | [64..4159] counts
// [4160..5695] fp32 biases | [8192..] W hi/lo ushort planes
#define WS_BIAS 4160
#define WS_WPLANES 8192
#define NWELEM 196608   // 12 * 16384

__device__ __forceinline__ float bf2f(unsigned int u) {
    return __builtin_bit_cast(float, u << 16);
}
__device__ __forceinline__ unsigned short f2bf(float f) {
    unsigned int x = __builtin_bit_cast(unsigned int, f);
    x += 0x7fff + ((x >> 16) & 1);   // round-to-nearest-even
    return (unsigned short)(x >> 16);
}
__device__ __forceinline__ float4f vmsub(float4f a, float s, float4f b) {
    a[0] -= s * b[0]; a[1] -= s * b[1]; a[2] -= s * b[2]; a[3] -= s * b[3];
    return a;
}

template<int ISF32>
__device__ __forceinline__ float ldv(const void* p, int i) {
    if (ISF32) return ((const float*)p)[i];
    return bf2f(((const unsigned short*)p)[i]);
}

// Per-wave dtype sniff: fp32 weights read as u16 pairs have uniform-random
// mantissa halves; bf16 weights have exponent fields in a narrow band.
__device__ __forceinline__ int detect_f32(const unsigned short* W1u, int lane) {
    unsigned int u = W1u[lane * 2];
    unsigned int e = (u >> 7) & 0xFF;
    int bad = (e < 64) || (e > 135);
    return __ballot(bad) != 0ull;
}

__device__ __forceinline__ float4f mfma16(short8 a, short8 b, float4f c) {
    return __builtin_amdgcn_mfma_f32_16x16x32_bf16(a, b, c, 0, 0, 0);
}

__device__ __forceinline__ void split8(float4f a, float4f b, short8& hi, short8& lo) {
#pragma unroll
    for (int j = 0; j < 4; ++j) {
        float v = a[j]; unsigned short h = f2bf(v);
        hi[j] = (short)h; lo[j] = (short)f2bf(v - bf2f(h));
        v = b[j]; h = f2bf(v);
        hi[4 + j] = (short)h; lo[4 + j] = (short)f2bf(v - bf2f(h));
    }
}

// ---- prep: W -> bf16 hi/lo planes, biases -> fp32, zero ticket ----
// (r12 lesson: inline per-matvec conversion costs ~450 cyc/matvec on the fwd
// critical path — the separate prep node is effectively free.)
__global__ void k_prep(const void* __restrict__ W1, const void* __restrict__ W2,
                       const void* __restrict__ W3, const void* __restrict__ b1,
                       const void* __restrict__ b2, const void* __restrict__ b3,
                       float* __restrict__ ws) {
    const int tid = threadIdx.x, bid = blockIdx.x;
    const int isf32 = detect_f32((const unsigned short*)W1, tid & 63);
    unsigned short* whi = (unsigned short*)(ws + WS_WPLANES);
    unsigned short* wlo = whi + NWELEM;
    if (bid < 96) {
        int s = (bid * 256 + tid) * 8;        // 96*256*8 = 196608
        int mat = s >> 14, off = s & 16383;   // mat = wsel*4 + layer
        int wsel = mat >> 2;
        const void* Wm = wsel == 0 ? W1 : (wsel == 1 ? W2 : W3);
        int src = (mat & 3) * 16384 + off;
        short8 hi, lo;
        if (isf32) {
            const float* p = (const float*)Wm + src;
            split8(*(const float4f*)p, *(const float4f*)(p + 4), hi, lo);
        } else {
            hi = *(const short8*)((const unsigned short*)Wm + src);
            lo = (short8){0, 0, 0, 0, 0, 0, 0, 0};
        }
        *(short8*)(whi + s) = hi;
        *(short8*)(wlo + s) = lo;
    } else {
        for (int e = tid; e < 1536; e += 256) {
            int bsel = e >> 9, idx = e & 511;
            const void* bp = bsel == 0 ? b1 : (bsel == 1 ? b2 : b3);
            ws[WS_BIAS + e] = isf32 ? ((const float*)bp)[idx]
                                    : bf2f(((const unsigned short*)bp)[idx]);
        }
        if (tid == 0) ((int*)ws)[0] = 0;   // finalize ticket
    }
}

// Weight fragments for one matvec, one 16-col group: [kk]{h,l}.
struct W4 { short8 v[8]; };

__device__ __forceinline__ W4 loadW4(const unsigned short* __restrict__ wh,
                                     const unsigned short* __restrict__ wl,
                                     int c0, int q) {
    W4 r;
#pragma unroll
    for (int kk = 0; kk < 4; ++kk) {
        const int kc = kk * 32 + q * 8;
        r.v[kk * 2 + 0] = *(const short8*)(wh + c0 * 128 + kc);
        r.v[kk * 2 + 1] = *(const short8*)(wl + c0 * 128 + kc);
    }
    return r;
}

// out[ROWS x 128] = act( in[ROWS x 128] @ W^T + bias ); ping-pong planes,
// one barrier per matvec; 8 waves x 16 cols each. Next matvec's weights
// prefetched right after the barrier (r11: -10us).
// MODE 0: out = leaky(v) | 1: out = res + v | 2: out = leaky(v)+count | 3: count only
template<int MODE>
__device__ __forceinline__ W4 matvec(const W4& w,
        const unsigned short* inh, const unsigned short* inl,
        unsigned short* outh, unsigned short* outl,
        const unsigned short* resh, const unsigned short* resl,
        const unsigned short* __restrict__ nwh, const unsigned short* __restrict__ nwl,
        const float* __restrict__ bias,
        int lane, int colb, int* cnt) {
    const int m = lane & 15, q = lane >> 4;
    const int c0 = colb + m;
    float b0 = bias[c0];
    float4f acc0 = {b0, b0, b0, b0};
    float4f acc1 = {b0, b0, b0, b0};
    __syncthreads();   // previous matvec's LDS writes visible
    W4 wn = loadW4(nwh, nwl, c0, q);   // prefetch next matvec's weights
#pragma unroll
    for (int kk = 0; kk < 4; ++kk) {
        const int kc = kk * 32 + q * 8;
        short8 x0h = *(const short8*)(inh + m * PITCH + kc);
        short8 x0l = *(const short8*)(inl + m * PITCH + kc);
        short8 x1h = *(const short8*)(inh + (16 + m) * PITCH + kc);
        short8 x1l = *(const short8*)(inl + (16 + m) * PITCH + kc);
        acc0 = mfma16(x0h, w.v[kk * 2 + 0], acc0);
        acc0 = mfma16(x0l, w.v[kk * 2 + 0], acc0);
        acc0 = mfma16(x0h, w.v[kk * 2 + 1], acc0);
        acc1 = mfma16(x1h, w.v[kk * 2 + 0], acc1);
        acc1 = mfma16(x1l, w.v[kk * 2 + 0], acc1);
        acc1 = mfma16(x1h, w.v[kk * 2 + 1], acc1);
    }
    int c[2][4];
#pragma unroll
    for (int rt = 0; rt < 2; ++rt) {
#pragma unroll
        for (int r = 0; r < 4; ++r) {
            float v0 = rt == 0 ? acc0[r] : acc1[r];
            int row = rt * 16 + q * 4 + r;
            int o0 = row * PITCH + c0;
            if (MODE == 1) v0 += bf2f(resh[o0]) + bf2f(resl[o0]);
            if (MODE >= 2) c[rt][r] = (v0 <= 0.0f);
            if (MODE == 0 || MODE == 2) v0 = v0 > 0.0f ? v0 : 0.1f * v0;
            if (MODE != 3) {
                unsigned short h0 = f2bf(v0);
                outh[o0] = h0; outl[o0] = f2bf(v0 - bf2f(h0));
            }
        }
    }
    if (MODE >= 2) {
#pragma unroll
        for (int rt = 0; rt < 2; ++rt) {
#pragma unroll
            for (int r = 0; r < 4; ++r) {
                int cc = c[rt][r];
                cc += __shfl_xor(cc, 1);
                cc += __shfl_xor(cc, 2);
                cc += __shfl_xor(cc, 4);
                cc += __shfl_xor(cc, 8);
                if (m == 0) atomicAdd(&cnt[rt * 16 + q * 4 + r], cc);
            }
        }
    }
    return wn;
}

template<int ISF32>
__device__ __forceinline__ void fwd(int bid, int tid, int lane, char* ldsb,
                                    const void* x, const float* ws, void* out,
                                    float* wsw) {
    unsigned short* P = (unsigned short*)ldsb;
    unsigned short* Ah = P;
    unsigned short* Al = P + 1 * ROWS * PITCH;
    unsigned short* Bh = P + 2 * ROWS * PITCH;
    unsigned short* Bl = P + 3 * ROWS * PITCH;
    unsigned short* Th = P + 4 * ROWS * PITCH;
    unsigned short* Tl = P + 5 * ROWS * PITCH;
    unsigned short* Uh = P + 6 * ROWS * PITCH;
    unsigned short* Ul = P + 7 * ROWS * PITCH;
    int* cnt = (int*)(P + 8 * ROWS * PITCH);
    const unsigned short* whi = (const unsigned short*)(ws + WS_WPLANES);
    const unsigned short* wlo = whi + NWELEM;
    const float* bias = ws + WS_BIAS;
    const int r0 = bid * ROWS;
    const int m = lane & 15, q = lane >> 4;
    const int colb = (tid >> 6) * 16;
    const int c0 = colb + m;
    // prefetch layer-0 w1 while staging x into LDS
    W4 wcur = loadW4(whi, wlo, c0, q);
    for (int e = tid; e < ROWS * 128; e += THREADS) {
        int r = e >> 7, c = e & 127;
        float v = ldv<ISF32>(x, (r0 + r) * 128 + c);
        unsigned short h = f2bf(v);
        Ah[r * PITCH + c] = h;
        Al[r * PITCH + c] = f2bf(v - bf2f(h));
    }
    if (tid < ROWS) cnt[tid] = 0;
    unsigned short *curh = Ah, *curl = Al, *othh = Bh, *othl = Bl;
#pragma unroll 1
    for (int layer = 0; layer < 4; ++layer) {
        const unsigned short* w1h = whi + (0 + layer) * 16384;
        const unsigned short* w1l = wlo + (0 + layer) * 16384;
        const unsigned short* w2h = whi + (4 + layer) * 16384;
        const unsigned short* w2l = wlo + (4 + layer) * 16384;
        const unsigned short* w3h = whi + (8 + layer) * 16384;
        const unsigned short* w3l = wlo + (8 + layer) * 16384;
        const unsigned short* n1h = whi + ((layer + 1) & 3) * 16384;  // next-layer w1
        const unsigned short* n1l = wlo + ((layer + 1) & 3) * 16384;
        const float* b1p = bias + layer * 128;
        const float* b2p = bias + 512 + layer * 128;
        const float* b3p = bias + 1024 + layer * 128;
        wcur = matvec<0>(wcur, curh, curl, Th, Tl, 0, 0, w2h, w2l, b1p, lane, colb, cnt);
        wcur = matvec<0>(wcur, Th, Tl, Uh, Ul, 0, 0, w3h, w3l, b2p, lane, colb, cnt);
        wcur = matvec<1>(wcur, Uh, Ul, othh, othl, curh, curl, w1h, w1l, b3p, lane, colb, cnt);
        wcur = matvec<2>(wcur, othh, othl, Th, Tl, 0, 0, w2h, w2l, b1p, lane, colb, cnt);
        wcur = matvec<3>(wcur, Th, Tl, Th, Tl, 0, 0, n1h, n1l, b2p, lane, colb, cnt);
        unsigned short* t;
        t = curh; curh = othh; othh = t;
        t = curl; curl = othl; othl = t;
    }
    __syncthreads();
    for (int e = tid; e < ROWS * 128; e += THREADS) {
        int r = e >> 7, c = e & 127;
        float v = bf2f(curh[r * PITCH + c]) + bf2f(curl[r * PITCH + c]);
        if (ISF32) ((float*)out)[(r0 + r) * 128 + c] = v;
        else ((unsigned short*)out)[(r0 + r) * 128 + c] = f2bf(v);
    }
    if (tid < ROWS) wsw[64 + r0 + tid] = (float)cnt[tid];
}

// ---- register-resident unpivoted LU, RANK-4 per barrier, 512 threads.
// r13 fit: cost/interval = a + c*rank^2, a~1.2us (barrier+latency), optimum
// rank* = sqrt(a/c) ~ 4. Doubling threads halves c (per-thread trailing and
// propagation work), keeping rank-4: predicted ~1.7us/interval.
// V[8]/thread: rows ty+16m (ty 0..15), cols 4tx..4tx+3. All register indices
// compile-time (r6 lesson: dynamic index -> scratch demotion).
template<int ISF32>
__device__ __forceinline__ float lu_logdet(int id, int tid, float* lds,
        const void* W1, const void* W2, const void* W3) {
    const int wsel = id % 3;
    const void* Wm = (wsel == 0 ? W1 : (wsel == 1 ? W2 : W3));
    const int ofs = (id / 3) * 16384;
    const int tx = tid & 31, ty = tid >> 5;   // ty 0..15
    float* rowbuf = lds;          // [2][4][128]: rows K..K+3
    float* colbuf = lds + 1024;   // [2][4][128]: cols K..K+3 packed [j][ty*8+m]
    float4f V[8];                 // A[ty+16m][4tx..4tx+3]
#pragma unroll
    for (int m = 0; m < 8; ++m) {
        int base = ofs + (ty + 16 * m) * 128 + 4 * tx;
        if (ISF32) {
            V[m] = *(const float4f*)((const float*)Wm + base);
        } else {
            ushort4 u = *(const ushort4*)((const unsigned short*)Wm + base);
            V[m] = (float4f){bf2f(u.x), bf2f(u.y), bf2f(u.z), bf2f(u.w)};
        }
    }
    // stage interval 0: rows 0..3 (ty<4, V[0]), cols 0..3 (owner tx==0)
    if (ty < 4) *(float4f*)&rowbuf[ty * 128 + 4 * tx] = V[0];
    if (tx == 0) {
#pragma unroll
        for (int j = 0; j < 4; ++j) {
            float4f t0 = {V[0][j], V[1][j], V[2][j], V[3][j]};
            float4f t1 = {V[4][j], V[5][j], V[6][j], V[7][j]};
            *(float4f*)&colbuf[j * 128 + ty * 8] = t0;
            *(float4f*)&colbuf[j * 128 + ty * 8 + 4] = t1;
        }
    }
    __syncthreads();
    float logacc = 0.0f;
#pragma unroll 1
    for (int kap = 0; kap < 32; ++kap) {
        const int K = kap * 4;
        const int buf = (kap & 1) * 512;
        float4f D[4], R[4], C[4][2];
#pragma unroll
        for (int j = 0; j < 4; ++j) {
            D[j] = *(const float4f*)&rowbuf[buf + j * 128 + K];       // broadcast
            R[j] = *(const float4f*)&rowbuf[buf + j * 128 + 4 * tx];
            C[j][0] = *(const float4f*)&colbuf[buf + j * 128 + ty * 8];
            C[j][1] = *(const float4f*)&colbuf[buf + j * 128 + ty * 8 + 4];
        }
        // 4x4 panel factorization, redundant per thread
        float p0 = D[0][0], i0 = 1.0f / p0;
        float l10 = D[1][0] * i0, l20 = D[2][0] * i0, l30 = D[3][0] * i0;
        D[1] = vmsub(D[1], l10, D[0]); R[1] = vmsub(R[1], l10, R[0]);
        D[2] = vmsub(D[2], l20, D[0]); R[2] = vmsub(R[2], l20, R[0]);
        D[3] = vmsub(D[3], l30, D[0]); R[3] = vmsub(R[3], l30, R[0]);
        float p1 = D[1][1], i1 = 1.0f / p1;
        float l21 = D[2][1] * i1, l31 = D[3][1] * i1;
        D[2] = vmsub(D[2], l21, D[1]); R[2] = vmsub(R[2], l21, R[1]);
        D[3] = vmsub(D[3], l31, D[1]); R[3] = vmsub(R[3], l31, R[1]);
        float p2 = D[2][2], i2 = 1.0f / p2;
        float l32 = D[3][2] * i2;
        D[3] = vmsub(D[3], l32, D[2]); R[3] = vmsub(R[3], l32, R[2]);
        float p3 = D[3][3], i3 = 1.0f / p3;
        logacc += __log2f(fabsf(p0)) + __log2f(fabsf(p1))
                + __log2f(fabsf(p2)) + __log2f(fabsf(p3));
        float iv[4] = {i0, i1, i2, i3};
        // cols -> multipliers (masked per row), propagate to later cols
#pragma unroll
        for (int i = 0; i < 4; ++i) {
#pragma unroll
            for (int cg = 0; cg < 2; ++cg) {
#pragma unroll
                for (int e = 0; e < 4; ++e) {
                    int r = ty + 16 * (cg * 4 + e);
                    C[i][cg][e] = (r > K + i) ? C[i][cg][e] * iv[i] : 0.0f;
                }
            }
#pragma unroll
            for (int j = i + 1; j < 4; ++j) {
                float uij = D[i][j];
                C[j][0] = vmsub(C[j][0], uij, C[i][0]);
                C[j][1] = vmsub(C[j][1], uij, C[i][1]);
            }
        }
        // rank-4 trailing update (V[m]: m = cg*4+e)
#pragma unroll
        for (int m = 0; m < 8; ++m) {
            float4f v = V[m];
            v = vmsub(v, C[0][m >> 2][m & 3], R[0]);
            v = vmsub(v, C[1][m >> 2][m & 3], R[1]);
            v = vmsub(v, C[2][m >> 2][m & 3], R[2]);
            v = vmsub(v, C[3][m >> 2][m & 3], R[3]);
            V[m] = v;
        }
        // stage next interval (rows/cols K+4..K+7)
        if (kap < 31) {
            const int nk = K + 4;
            const int nbuf = ((kap + 1) & 1) * 512;
            // rows nk..nk+3: owners ty in [nk&15, (nk&15)+3], V index nk>>4 (uniform)
            if ((ty >> 2) == ((nk & 15) >> 2)) {
                float4f val;
                switch (nk >> 4) {               // uniform switch, static reg index
                case 0:  val = V[0]; break; case 1:  val = V[1]; break;
                case 2:  val = V[2]; break; case 3:  val = V[3]; break;
                case 4:  val = V[4]; break; case 5:  val = V[5]; break;
                case 6:  val = V[6]; break; default: val = V[7]; break;
                }
                *(float4f*)&rowbuf[nbuf + (ty & 3) * 128 + 4 * tx] = val;
            }
            if (tx == (nk >> 2)) {               // owner of cols nk..nk+3
#pragma unroll
                for (int j = 0; j < 4; ++j) {
                    float4f t0 = {V[0][j], V[1][j], V[2][j], V[3][j]};
                    float4f t1 = {V[4][j], V[5][j], V[6][j], V[7][j]};
                    *(float4f*)&colbuf[nbuf + j * 128 + ty * 8] = t0;
                    *(float4f*)&colbuf[nbuf + j * 128 + ty * 8 + 4] = t1;
                }
            }
        }
        __syncthreads();   // one barrier per 4 pivots
    }
    return logacc * LN2;
}

__global__ __launch_bounds__(THREADS, 1) void k_main(
        const void* __restrict__ x,
        const void* __restrict__ W1, const void* __restrict__ b1,
        const void* __restrict__ W2, const void* __restrict__ b2,
        const void* __restrict__ W3, const void* __restrict__ b3,
        void* __restrict__ out, float* __restrict__ ws) {
    extern __shared__ __align__(16) char ldsb[];
    __shared__ int s_last;
    const int tid = threadIdx.x;
    const int lane = tid & 63;
    const int isf32 = detect_f32((const unsigned short*)W1, lane);

    if (blockIdx.x < 12) {
        float ld = isf32 ? lu_logdet<1>(blockIdx.x, tid, (float*)ldsb, W1, W2, W3)
                         : lu_logdet<0>(blockIdx.x, tid, (float*)ldsb, W1, W2, W3);
        if (tid == 0) ws[2 + blockIdx.x] = ld;
    } else {
        const int bid = blockIdx.x - 12;
        if (isf32) fwd<1>(bid, tid, lane, ldsb, x, ws, out, ws);
        else       fwd<0>(bid, tid, lane, ldsb, x, ws, out, ws);
    }

    // ---- last-block finalize ----
    __threadfence();
    if (tid == 0) s_last = (atomicAdd((int*)ws, 1) == NBLK - 1);
    __syncthreads();
    if (!s_last) return;
    __threadfence();   // acquire: other blocks' ws writes now visible
    float s = 0.0f;
#pragma unroll
    for (int i = 0; i < 12; ++i) s += ws[2 + i];
    for (int b = tid; b < 4096; b += THREADS) {
        float v = s + LOG_SLOPE * ws[64 + b];
        if (isf32) ((float*)out)[524288 + b] = v;
        else ((unsigned short*)out)[524288 + b] = f2bf(v);
    }
}

extern "C" void kernel_launch(void* const* d_in, const int* in_sizes, int n_in,
                              void* d_out, int out_size, void* d_ws, size_t ws_size,
                              hipStream_t stream) {
    const void* x  = d_in[0];
    const void* W1 = d_in[1];
    const void* b1 = d_in[2];
    const void* W2 = d_in[3];
    const void* b2 = d_in[4];
    const void* W3 = d_in[5];
    const void* b3 = d_in[6];
    float* ws = (float*)d_ws;

    hipLaunchKernelGGL(k_prep, dim3(97), dim3(256), 0, stream,
                       W1, W2, W3, b1, b2, b3, ws);
    hipLaunchKernelGGL(k_main, dim3(NBLK), dim3(THREADS), LDS_BYTES, stream,
                       x, W1, b1, W2, b2, W3, b3, d_out, ws);
}